// Round 11
// baseline (183.150 us; speedup 1.0000x reference)
//
#include <hip/hip_runtime.h>

// Problem constants (B=8, S=4096, D=64, ds=16)
#define BATCH   8
#define SEQ     4096
#define DM      64
#define DS      16
#define BS      (BATCH*SEQ)      // 32768 timesteps
#define CHUNK   16               // scan chunk length
#define NCHT    (BS/CHUNK)       // 2048 chunks total
#define SG      16               // chunks per supergroup
#define NSG     (NCHT/SG)        // 128 supergroups (16 per batch)

typedef __attribute__((ext_vector_type(8))) __bf16 bf16x8;
typedef __attribute__((ext_vector_type(4))) float  f32x4;

__device__ __forceinline__ unsigned short f2bf(float f) {
  unsigned int u = __float_as_uint(f);
  u += 0x7fffu + ((u >> 16) & 1u);          // RNE (finite values)
  return (unsigned short)(u >> 16);
}
__device__ __forceinline__ float bflo(unsigned int u) { return __uint_as_float(u << 16); }
__device__ __forceinline__ float bfhi(unsigned int u) { return __uint_as_float(u & 0xffff0000u); }

// LDS A-tile strides (ushorts): per-i 20 (40B), per-t 324 (648B)
#define AS_I 20
#define AS_T 324

// ---------------------------------------------------------------------------
// K0: transpose+cast weights.  576 blocks.
// ---------------------------------------------------------------------------
__global__ __launch_bounds__(256) void k0_castw(
    const float* __restrict__ WA, const float* __restrict__ WB,
    const float* __restrict__ WC,
    unsigned short* __restrict__ WAt, unsigned short* __restrict__ WBt,
    unsigned short* __restrict__ WCt)
{
  const int o = blockIdx.x * 256 + threadIdx.x;
  if (o < 16384) {
    const int c = o >> 6, e = o & 63;
    WAt[o] = f2bf(WA[e * 256 + c]);
  } else if (o < 16384 + 65536) {
    const int p = o - 16384;
    const int c = p >> 6, e = p & 63;
    WBt[p] = f2bf(WB[e * 1024 + c]);
  } else {
    const int p = o - 16384 - 65536;
    const int c = p >> 6, e = p & 63;
    WCt[p] = f2bf(WC[e * 1024 + c]);
  }
}

// ---------------------------------------------------------------------------
// G1: 64-t blocks, 256 thr (4 waves); wave w owns chunk blk*4+w (16 t).
// Register budget deliberately open ((256,1)) + explicit weight-frag
// double-buffering so L2 latency overlaps MFMA work.
// ---------------------------------------------------------------------------
__global__ __launch_bounds__(256, 1) void g1(
    const float* __restrict__ x, const unsigned short* __restrict__ WBt,
    const float* __restrict__ bB, const unsigned short* __restrict__ WAt,
    const float* __restrict__ bA, unsigned short* __restrict__ xb,
    unsigned short* __restrict__ Wt_ws, float* __restrict__ u_ws,
    float* __restrict__ P_ws, float* __restrict__ v_ws)
{
  __shared__ __align__(16) unsigned char smem[64 * AS_T * 2];   // 41472 B
  float (*xs)[68]     = (float (*)[68])smem;                    // 17408 B
  float* bBs          = (float*)(smem + 17408);                 //  4096 B
  unsigned short* As  = (unsigned short*)smem;
  __shared__ __align__(16) float bxs[64][16];
  __shared__ __align__(16) float us[4][16];

  const int tid  = threadIdx.x;
  const int lane = tid & 63;
  const int l15  = lane & 15;
  const int quad = lane >> 4;
  const int w    = tid >> 6;             // 0..3
  const int t0   = blockIdx.x * 64;
  const int twl  = w * 16;

  { // stage fp32 x tile (64x64 = 1024 float4) + bB; zero us
    const float4* xg = (const float4*)(x + (size_t)t0 * DM);
    #pragma unroll
    for (int i = 0; i < 4; ++i) {
      const int f4 = tid + 256 * i;
      ((float4*)&xs[f4 >> 4][0])[f4 & 15] = xg[f4];
    }
    ((float4*)bBs)[tid] = ((const float4*)bB)[tid];
    if (tid < 64) us[tid >> 4][tid & 15] = 0.f;
  }
  __syncthreads();

  // ---- build A-operand frags from LDS; store to xb for g2 ----
  bf16x8 a0, a1;
  {
    const int row = twl + l15;
    union { bf16x8 v; ushort4 s[2]; } ua, ub;
    float4 p0 = *(const float4*)&xs[row][quad * 8];
    float4 p1 = *(const float4*)&xs[row][quad * 8 + 4];
    float4 p2 = *(const float4*)&xs[row][32 + quad * 8];
    float4 p3 = *(const float4*)&xs[row][32 + quad * 8 + 4];
    ua.s[0] = (ushort4){f2bf(p0.x), f2bf(p0.y), f2bf(p0.z), f2bf(p0.w)};
    ua.s[1] = (ushort4){f2bf(p1.x), f2bf(p1.y), f2bf(p1.z), f2bf(p1.w)};
    ub.s[0] = (ushort4){f2bf(p2.x), f2bf(p2.y), f2bf(p2.z), f2bf(p2.w)};
    ub.s[1] = (ushort4){f2bf(p3.x), f2bf(p3.y), f2bf(p3.z), f2bf(p3.w)};
    a0 = ua.v; a1 = ub.v;
    unsigned short* xp = xb + (size_t)(t0 + row) * 64 + quad * 8;
    *(bf16x8*)xp        = a0;
    *(bf16x8*)(xp + 32) = a1;
  }

  // ---- B-phase: Bx -> bxs, double-buffered weight frags ----
  {
    bf16x8 wf[8];
    #pragma unroll
    for (int r = 0; r < 4; ++r) {
      const bf16x8* wv = (const bf16x8*)(WBt + (size_t)(r * 16 + l15) * 64);
      wf[2*r]   = wv[quad];
      wf[2*r+1] = wv[quad + 4];
    }
    #pragma unroll 1
    for (int n = 0; n < 16; ++n) {
      bf16x8 nf[8];
      if (n < 15) {
        #pragma unroll
        for (int r = 0; r < 4; ++r) {
          const bf16x8* wv = (const bf16x8*)(WBt + (size_t)(((n+1) * 4 + r) * 16 + l15) * 64);
          nf[2*r]   = wv[quad];
          nf[2*r+1] = wv[quad + 4];
        }
      }
      f32x4 ac[4];
      #pragma unroll
      for (int r = 0; r < 4; ++r) {
        f32x4 t = {0.f, 0.f, 0.f, 0.f};
        t = __builtin_amdgcn_mfma_f32_16x16x32_bf16(a0, wf[2*r],   t, 0, 0, 0);
        t = __builtin_amdgcn_mfma_f32_16x16x32_bf16(a1, wf[2*r+1], t, 0, 0, 0);
        ac[r] = t;
      }
      float part[4] = {0.f, 0.f, 0.f, 0.f};
      #pragma unroll
      for (int r = 0; r < 4; ++r) {
        const float bb = bBs[n * 64 + r * 16 + l15];
        #pragma unroll
        for (int reg = 0; reg < 4; ++reg) {
          const int tl = twl + quad * 4 + reg;
          part[reg] = fmaf(ac[r][reg] + bb, xs[tl][r * 16 + l15], part[reg]);
        }
      }
      #pragma unroll
      for (int off = 1; off < 16; off <<= 1) {
        #pragma unroll
        for (int reg = 0; reg < 4; ++reg)
          part[reg] += __shfl_xor(part[reg], off, 64);
      }
      if (l15 == 0) {
        #pragma unroll
        for (int reg = 0; reg < 4; ++reg)
          bxs[twl + quad * 4 + reg][n] = part[reg];
      }
      #pragma unroll
      for (int q = 0; q < 8; ++q) wf[q] = nf[q];
    }
  }
  __syncthreads();   // bxs ready; xs/bBs dead

  // ---- A-phase: A tile into As, 2-frag lookahead ----
  {
    bf16x8 c0, c1;
    {
      const bf16x8* wv = (const bf16x8*)(WAt + (size_t)(l15) * 64);
      c0 = wv[quad]; c1 = wv[quad + 4];
    }
    #pragma unroll 1
    for (int ns = 0; ns < 16; ++ns) {
      bf16x8 n0, n1;
      if (ns < 15) {
        const bf16x8* wv = (const bf16x8*)(WAt + (size_t)((ns+1) * 16 + l15) * 64);
        n0 = wv[quad]; n1 = wv[quad + 4];
      }
      f32x4 acc = {0.f, 0.f, 0.f, 0.f};
      acc = __builtin_amdgcn_mfma_f32_16x16x32_bf16(a0, c0, acc, 0, 0, 0);
      acc = __builtin_amdgcn_mfma_f32_16x16x32_bf16(a1, c1, acc, 0, 0, 0);
      const float bias = bA[ns * 16 + l15];
      #pragma unroll
      for (int r = 0; r < 4; ++r)
        As[(twl + quad * 4 + r) * AS_T + ns * AS_I + l15] = f2bf(acc[r] + bias);
      c0 = n0; c1 = n1;
    }
  }
  __syncthreads();

  // ---- scan: every wave runs its own 16-step chunk ----
  {
    bf16x8 wb;          // W in B-operand layout: wb[j] = W[quad*8+j][l15]
    #pragma unroll
    for (int j = 0; j < 8; ++j) wb[j] = (__bf16)((quad * 8 + j == l15) ? 1.f : 0.f);
    f32x4 d = {0.f, 0.f, 0.f, 0.f};
    const int qq = quad & 1;

    // preload row t=0
    const unsigned short* rp = &As[twl * AS_T + l15 * AS_I];
    uint2 r0 = *(const uint2*)(rp);
    uint2 r1 = *(const uint2*)(rp + 4);
    uint2 r2 = *(const uint2*)(rp + 8);
    uint2 r3 = *(const uint2*)(rp + 12);

    #pragma unroll 1
    for (int t = 0; t < CHUNK; ++t) {
      const int tl = twl + t;

      uint4 abits;
      if (quad == 0)      abits = make_uint4(r0.x, r0.y, r1.x, r1.y);
      else if (quad == 1) abits = make_uint4(r2.x, r2.y, r3.x, r3.y);
      else                abits = make_uint4(0u, 0u, 0u, 0u);
      bf16x8 af = *(bf16x8*)&abits;

      // prefetch next row (t+1) while MFMA/shfl chain runs
      uint2 p0, p1, p2, p3;
      if (t < CHUNK - 1) {
        const unsigned short* np = &As[(tl + 1) * AS_T + l15 * AS_I];
        p0 = *(const uint2*)(np);
        p1 = *(const uint2*)(np + 4);
        p2 = *(const uint2*)(np + 8);
        p3 = *(const uint2*)(np + 12);
      }

      f32x4 z4 = {0.f, 0.f, 0.f, 0.f};
      d = __builtin_amdgcn_mfma_f32_16x16x32_bf16(af, wb, z4, 0, 0, 0);

      float nu = bxs[tl][l15];
      {
        float4 U0 = *(const float4*)&us[w][0];
        float4 U1 = *(const float4*)&us[w][4];
        float4 U2 = *(const float4*)&us[w][8];
        float4 U3 = *(const float4*)&us[w][12];
        nu = fmaf(bflo(r0.x), U0.x, nu); nu = fmaf(bfhi(r0.x), U0.y, nu);
        nu = fmaf(bflo(r0.y), U0.z, nu); nu = fmaf(bfhi(r0.y), U0.w, nu);
        nu = fmaf(bflo(r1.x), U1.x, nu); nu = fmaf(bfhi(r1.x), U1.y, nu);
        nu = fmaf(bflo(r1.y), U1.z, nu); nu = fmaf(bfhi(r1.y), U1.w, nu);
        nu = fmaf(bflo(r2.x), U2.x, nu); nu = fmaf(bfhi(r2.x), U2.y, nu);
        nu = fmaf(bflo(r2.y), U2.z, nu); nu = fmaf(bfhi(r2.y), U2.w, nu);
        nu = fmaf(bflo(r3.x), U3.x, nu); nu = fmaf(bfhi(r3.x), U3.y, nu);
        nu = fmaf(bflo(r3.y), U3.z, nu); nu = fmaf(bfhi(r3.y), U3.w, nu);
      }

      bf16x8 nb;
      nb[0] = (__bf16)__shfl(d[0], (2 * qq + 0) * 16 + l15, 64);
      nb[1] = (__bf16)__shfl(d[1], (2 * qq + 0) * 16 + l15, 64);
      nb[2] = (__bf16)__shfl(d[2], (2 * qq + 0) * 16 + l15, 64);
      nb[3] = (__bf16)__shfl(d[3], (2 * qq + 0) * 16 + l15, 64);
      nb[4] = (__bf16)__shfl(d[0], (2 * qq + 1) * 16 + l15, 64);
      nb[5] = (__bf16)__shfl(d[1], (2 * qq + 1) * 16 + l15, 64);
      nb[6] = (__bf16)__shfl(d[2], (2 * qq + 1) * 16 + l15, 64);
      nb[7] = (__bf16)__shfl(d[3], (2 * qq + 1) * 16 + l15, 64);
      wb = nb;

      if (quad == 0) {
        us[w][l15] = nu;
        bxs[tl][l15] = nu;                 // u prefix in place
      }
      #pragma unroll
      for (int r = 0; r < 4; ++r)
        As[tl * AS_T + (quad * 4 + r) * AS_I + l15] = f2bf(d[r]);

      r0 = p0; r1 = p1; r2 = p2; r3 = p3;
    }

    const int chunk = blockIdx.x * 4 + w;
    #pragma unroll
    for (int r = 0; r < 4; ++r)
      P_ws[(size_t)chunk * 256 + (quad * 4 + r) * 16 + l15] = d[r];
    if (quad == 0) v_ws[(size_t)chunk * DS + l15] = us[w][l15];
  }
  __syncthreads();

  // ---- flush Wt (64x256 bf16 = 2048 uint4) + u (256 float4) coalesced ----
  {
    uint4* Wg = (uint4*)(Wt_ws + (size_t)t0 * 256);
    #pragma unroll 1
    for (int z = 0; z < 8; ++z) {
      const int p4 = z * 256 + tid;
      const int f  = p4 * 8;
      const int t  = f >> 8, i = (f >> 4) & 15, k = f & 15;
      const unsigned short* sp = &As[t * AS_T + i * AS_I + k];
      uint2 lo = *(const uint2*)(sp);
      uint2 hi = *(const uint2*)(sp + 4);
      Wg[p4] = make_uint4(lo.x, lo.y, hi.x, hi.y);
    }
    ((float4*)(u_ws + (size_t)t0 * DS))[tid] = ((const float4*)&bxs[0][0])[tid];
  }
}

// ---------------------------------------------------------------------------
// K3a: supergroup fold.  One wave per supergroup s (128 total).
// ---------------------------------------------------------------------------
__global__ __launch_bounds__(256) void k3a(
    const float* __restrict__ P_ws, const float* __restrict__ v_ws,
    float* __restrict__ Q_ws, float* __restrict__ w_ws)
{
  __shared__ float wsv[4][16];
  const int tid  = threadIdx.x;
  const int lane = tid & 63;
  const int l15  = lane & 15;
  const int quad = lane >> 4;
  const int wv   = tid >> 6;
  const int s    = blockIdx.x * 4 + wv;
  const int qq   = quad & 1;

  if (lane < 16) wsv[wv][lane] = 0.f;
  bf16x8 wb;
  #pragma unroll
  for (int j = 0; j < 8; ++j) wb[j] = (__bf16)((quad * 8 + j == l15) ? 1.f : 0.f);
  f32x4 d = {0.f, 0.f, 0.f, 0.f};

  #pragma unroll 1
  for (int t = 0; t < SG; ++t) {
    const int chunk = s * SG + t;
    float4 p0 = {0.f,0.f,0.f,0.f}, p1 = {0.f,0.f,0.f,0.f};
    if (quad < 2) {
      const float4* pr = (const float4*)(P_ws + (size_t)chunk * 256 + l15 * 16 + quad * 8);
      p0 = pr[0]; p1 = pr[1];
    }
    bf16x8 af;
    af[0] = (__bf16)p0.x; af[1] = (__bf16)p0.y; af[2] = (__bf16)p0.z; af[3] = (__bf16)p0.w;
    af[4] = (__bf16)p1.x; af[5] = (__bf16)p1.y; af[6] = (__bf16)p1.z; af[7] = (__bf16)p1.w;

    f32x4 z4 = {0.f, 0.f, 0.f, 0.f};
    d = __builtin_amdgcn_mfma_f32_16x16x32_bf16(af, wb, z4, 0, 0, 0);

    float part = 0.f;
    if (quad < 2) {
      const float* wrow = &wsv[wv][quad * 8];
      part = p0.x*wrow[0] + p0.y*wrow[1] + p0.z*wrow[2] + p0.w*wrow[3]
           + p1.x*wrow[4] + p1.y*wrow[5] + p1.z*wrow[6] + p1.w*wrow[7];
    }
    part += __shfl_xor(part, 16, 64);
    const float nv = v_ws[(size_t)chunk * DS + l15];

    bf16x8 nb;
    nb[0] = (__bf16)__shfl(d[0], (2 * qq + 0) * 16 + l15, 64);
    nb[1] = (__bf16)__shfl(d[1], (2 * qq + 0) * 16 + l15, 64);
    nb[2] = (__bf16)__shfl(d[2], (2 * qq + 0) * 16 + l15, 64);
    nb[3] = (__bf16)__shfl(d[3], (2 * qq + 0) * 16 + l15, 64);
    nb[4] = (__bf16)__shfl(d[0], (2 * qq + 1) * 16 + l15, 64);
    nb[5] = (__bf16)__shfl(d[1], (2 * qq + 1) * 16 + l15, 64);
    nb[6] = (__bf16)__shfl(d[2], (2 * qq + 1) * 16 + l15, 64);
    nb[7] = (__bf16)__shfl(d[3], (2 * qq + 1) * 16 + l15, 64);
    wb = nb;

    if (quad == 0) wsv[wv][l15] = part + nv;
  }

  #pragma unroll
  for (int r = 0; r < 4; ++r)
    Q_ws[(size_t)s * 256 + (quad * 4 + r) * 16 + l15] = d[r];
  if (quad == 0) w_ws[(size_t)s * DS + l15] = wsv[wv][l15];
}

// ---------------------------------------------------------------------------
// K3b: serial scan over 16 supergroups per batch (8 b x 16 lanes = 128 thr).
// ---------------------------------------------------------------------------
__global__ __launch_bounds__(128) void k3b(
    const float* __restrict__ Q_ws, const float* __restrict__ w_ws,
    float* __restrict__ hbg_ws)
{
  const int tid = threadIdx.x;
  const int b = tid >> 4;
  const int r = tid & 15;
  float h = 0.f;

  #pragma unroll 1
  for (int g = 0; g < 16; ++g) {
    const int s = b * 16 + g;
    const float4* Pr = (const float4*)&Q_ws[(size_t)s * 256 + r * 16];
    float4 c0 = Pr[0], c1 = Pr[1], c2 = Pr[2], c3 = Pr[3];
    const float vc = w_ws[(size_t)s * DS + r];
    hbg_ws[(size_t)s * DS + r] = h;
    float acc = vc;
    acc += c0.x*__shfl(h, 0,16) + c0.y*__shfl(h, 1,16) + c0.z*__shfl(h, 2,16) + c0.w*__shfl(h, 3,16);
    acc += c1.x*__shfl(h, 4,16) + c1.y*__shfl(h, 5,16) + c1.z*__shfl(h, 6,16) + c1.w*__shfl(h, 7,16);
    acc += c2.x*__shfl(h, 8,16) + c2.y*__shfl(h, 9,16) + c2.z*__shfl(h,10,16) + c2.w*__shfl(h,11,16);
    acc += c3.x*__shfl(h,12,16) + c3.y*__shfl(h,13,16) + c3.z*__shfl(h,14,16) + c3.w*__shfl(h,15,16);
    h = acc;
  }
}

// ---------------------------------------------------------------------------
// K3c: within-supergroup replay: entering state of each chunk.
// ---------------------------------------------------------------------------
__global__ __launch_bounds__(256) void k3c(
    const float* __restrict__ P_ws, const float* __restrict__ v_ws,
    const float* __restrict__ hbg_ws, float* __restrict__ hb_ws)
{
  const int tid = threadIdx.x;
  const int s = blockIdx.x * 16 + (tid >> 4);
  const int r = tid & 15;
  float h = hbg_ws[(size_t)s * DS + r];

  #pragma unroll 1
  for (int t = 0; t < SG; ++t) {
    const int chunk = s * SG + t;
    const float4* Pr = (const float4*)&P_ws[(size_t)chunk * 256 + r * 16];
    float4 c0 = Pr[0], c1 = Pr[1], c2 = Pr[2], c3 = Pr[3];
    const float vc = v_ws[(size_t)chunk * DS + r];
    hb_ws[(size_t)chunk * DS + r] = h;
    float acc = vc;
    acc += c0.x*__shfl(h, 0,16) + c0.y*__shfl(h, 1,16) + c0.z*__shfl(h, 2,16) + c0.w*__shfl(h, 3,16);
    acc += c1.x*__shfl(h, 4,16) + c1.y*__shfl(h, 5,16) + c1.z*__shfl(h, 6,16) + c1.w*__shfl(h, 7,16);
    acc += c2.x*__shfl(h, 8,16) + c2.y*__shfl(h, 9,16) + c2.z*__shfl(h,10,16) + c2.w*__shfl(h,11,16);
    acc += c3.x*__shfl(h,12,16) + c3.y*__shfl(h,13,16) + c3.z*__shfl(h,14,16) + c3.w*__shfl(h,15,16);
    h = acc;
  }
}

// ---------------------------------------------------------------------------
// G2: per block 64 t.  Phase 1: hs = W_t h_entry + u_t into LDS.
// Phase 2: out = sum_n (x@WC + bC)[n,d] * hs[n] via MFMA, frag double-buffer.
// ---------------------------------------------------------------------------
__global__ __launch_bounds__(256, 1) void g2(
    const unsigned short* __restrict__ xb, const unsigned short* __restrict__ WCt,
    const float* __restrict__ bC, const unsigned short* __restrict__ Wt_ws,
    const float* __restrict__ u_ws, const float* __restrict__ hb_ws,
    float* __restrict__ out)
{
  __shared__ float hsh[64][17];
  __shared__ float bCs[1024];
  const int tid  = threadIdx.x;
  const int lane = tid & 63;
  const int l15  = lane & 15;
  const int quad = lane >> 4;
  const int w    = tid >> 6;
  const int t0   = blockIdx.x * 64;
  const int twl  = w * 16;

  ((float4*)bCs)[tid] = ((const float4*)bC)[tid];

  #pragma unroll
  for (int z = 0; z < 4; ++z) {
    const int gcell = z * 256 + tid;
    const int tl = gcell >> 4, i = gcell & 15;
    const int t = t0 + tl;
    const uint4* wr = (const uint4*)(Wt_ws + (size_t)t * 256 + i * 16);
    uint4 wa = wr[0], wbv = wr[1];
    const float4* hp = (const float4*)(hb_ws + (size_t)(t >> 4) * DS);  // CHUNK=16
    float4 h0 = hp[0], h1 = hp[1], h2 = hp[2], h3 = hp[3];
    float acc = u_ws[(size_t)t * DS + i];
    acc = fmaf(bflo(wa.x),  h0.x, acc); acc = fmaf(bfhi(wa.x),  h0.y, acc);
    acc = fmaf(bflo(wa.y),  h0.z, acc); acc = fmaf(bfhi(wa.y),  h0.w, acc);
    acc = fmaf(bflo(wa.z),  h1.x, acc); acc = fmaf(bfhi(wa.z),  h1.y, acc);
    acc = fmaf(bflo(wa.w),  h1.z, acc); acc = fmaf(bfhi(wa.w),  h1.w, acc);
    acc = fmaf(bflo(wbv.x), h2.x, acc); acc = fmaf(bfhi(wbv.x), h2.y, acc);
    acc = fmaf(bflo(wbv.y), h2.z, acc); acc = fmaf(bfhi(wbv.y), h2.w, acc);
    acc = fmaf(bflo(wbv.z), h3.x, acc); acc = fmaf(bfhi(wbv.z), h3.y, acc);
    acc = fmaf(bflo(wbv.w), h3.z, acc); acc = fmaf(bfhi(wbv.w), h3.w, acc);
    hsh[tl][i] = acc;
  }

  const bf16x8* xv = (const bf16x8*)(xb + (size_t)(t0 + twl + l15) * 64);
  bf16x8 a0 = xv[quad];
  bf16x8 a1 = xv[quad + 4];
  __syncthreads();

  f32x4 ota[4];
  #pragma unroll
  for (int r = 0; r < 4; ++r) ota[r] = (f32x4){0.f, 0.f, 0.f, 0.f};

  {
    bf16x8 wf[8];
    #pragma unroll
    for (int r = 0; r < 4; ++r) {
      const bf16x8* wv = (const bf16x8*)(WCt + (size_t)(r * 16 + l15) * 64);
      wf[2*r]   = wv[quad];
      wf[2*r+1] = wv[quad + 4];
    }
    #pragma unroll 1
    for (int n = 0; n < 16; ++n) {
      bf16x8 nf[8];
      if (n < 15) {
        #pragma unroll
        for (int r = 0; r < 4; ++r) {
          const bf16x8* wv = (const bf16x8*)(WCt + (size_t)(((n+1) * 4 + r) * 16 + l15) * 64);
          nf[2*r]   = wv[quad];
          nf[2*r+1] = wv[quad + 4];
        }
      }
      f32x4 ac[4];
      #pragma unroll
      for (int r = 0; r < 4; ++r) {
        f32x4 t = {0.f, 0.f, 0.f, 0.f};
        t = __builtin_amdgcn_mfma_f32_16x16x32_bf16(a0, wf[2*r],   t, 0, 0, 0);
        t = __builtin_amdgcn_mfma_f32_16x16x32_bf16(a1, wf[2*r+1], t, 0, 0, 0);
        ac[r] = t;
      }
      float hn[4];
      #pragma unroll
      for (int reg = 0; reg < 4; ++reg) hn[reg] = hsh[twl + quad * 4 + reg][n];
      #pragma unroll
      for (int r = 0; r < 4; ++r) {
        const float bc = bCs[n * 64 + r * 16 + l15];
        #pragma unroll
        for (int reg = 0; reg < 4; ++reg)
          ota[r][reg] = fmaf(ac[r][reg] + bc, hn[reg], ota[r][reg]);
      }
      #pragma unroll
      for (int q = 0; q < 8; ++q) wf[q] = nf[q];
    }
  }

  #pragma unroll
  for (int r = 0; r < 4; ++r)
    #pragma unroll
    for (int reg = 0; reg < 4; ++reg)
      out[(size_t)(t0 + twl + quad * 4 + reg) * DM + r * 16 + l15] = ota[r][reg];
}

// ---------------------------------------------------------------------------
extern "C" void kernel_launch(void* const* d_in, const int* in_sizes, int n_in,
                              void* d_out, int out_size, void* d_ws, size_t ws_size,
                              hipStream_t stream) {
  const float* x  = (const float*)d_in[0];
  const float* WA = (const float*)d_in[1];
  const float* bA = (const float*)d_in[2];
  const float* WB = (const float*)d_in[3];
  const float* bB = (const float*)d_in[4];
  const float* WC = (const float*)d_in[5];
  const float* bC = (const float*)d_in[6];
  float* out = (float*)d_out;

  float* ws     = (float*)d_ws;
  float* P_ws   = ws;                               // NCHT*256 (2 MB)
  float* v_ws   = P_ws   + (size_t)NCHT * 256;      // NCHT*16
  float* u_ws   = v_ws   + (size_t)NCHT * DS;       // BS*16
  float* Q_ws   = u_ws   + (size_t)BS * DS;         // NSG*256
  float* w_ws   = Q_ws   + (size_t)NSG * 256;       // NSG*16
  float* hbg_ws = w_ws   + (size_t)NSG * DS;        // NSG*16
  float* hb_ws  = hbg_ws + (size_t)NSG * DS;        // NCHT*16
  unsigned short* xb    = (unsigned short*)(hb_ws + (size_t)NCHT * DS);
  unsigned short* WAt   = xb  + (size_t)BS * 64;    // 16384
  unsigned short* WBt   = WAt + 256 * 64;           // 65536
  unsigned short* WCt   = WBt + 1024 * 64;          // 65536
  unsigned short* Wt_ws = WCt + 1024 * 64;          // BS*256 (16.8 MB)

  k0_castw<<<576,      256, 0, stream>>>(WA, WB, WC, WAt, WBt, WCt);
  g1      <<<BS / 64,  256, 0, stream>>>(x, WBt, bB, WAt, bA, xb, Wt_ws, u_ws, P_ws, v_ws);
  k3a     <<<NSG / 4,  256, 0, stream>>>(P_ws, v_ws, Q_ws, w_ws);
  k3b     <<<1,        128, 0, stream>>>(Q_ws, w_ws, hbg_ws);
  k3c     <<<NSG / 16, 256, 0, stream>>>(P_ws, v_ws, hbg_ws, hb_ws);
  g2      <<<BS / 64,  256, 0, stream>>>(xb, WCt, bC, Wt_ws, u_ws, hb_ws, out);
}